// Round 12
// baseline (576.394 us; speedup 1.0000x reference)
//
#include <hip/hip_runtime.h>
#include <hip/hip_fp8.h>
#include <math.h>

constexpr int NN = 100000;   // nodes
constexpr int NE = 1600000;  // edges
constexpr int H  = 128;      // feat/hidden
constexpr int NG = 100;      // graphs
constexpr int NC = 10;       // classes
constexpr int NB = 98;       // CSR buckets (dst >> 10)
constexpr int CAP = 18432;   // per-bucket staging capacity
constexpr int NSLOT = 256;   // BN stats partial slots

typedef _Float16 half8 __attribute__((ext_vector_type(8)));
typedef _Float16 half4 __attribute__((ext_vector_type(4)));
typedef float    f32x4 __attribute__((ext_vector_type(4)));
typedef float    f32x2 __attribute__((ext_vector_type(2)));

// ---- fp8 e4m3 (OCP) helpers ----
static __device__ __forceinline__ unsigned char ftofp8(float f) {
#if __has_builtin(__builtin_amdgcn_cvt_pk_fp8_f32)
    int r = __builtin_amdgcn_cvt_pk_fp8_f32(f, f, 0, false);
    return (unsigned char)(r & 0xff);
#else
    __hip_fp8_e4m3 v(f);
    unsigned char b; __builtin_memcpy(&b, &v, 1); return b;
#endif
}

static __device__ __forceinline__ float4 fp8x4tof(unsigned int u) {
#if __has_builtin(__builtin_amdgcn_cvt_pk_f32_fp8)
    f32x2 lo = __builtin_amdgcn_cvt_pk_f32_fp8(u, false);
    f32x2 hi = __builtin_amdgcn_cvt_pk_f32_fp8(u, true);
    return make_float4(lo.x, lo.y, hi.x, hi.y);
#else
    float r[4];
    #pragma unroll
    for (int i = 0; i < 4; i++) {
        unsigned char b = (u >> (8 * i)) & 0xff;
        __hip_fp8_e4m3 v; __builtin_memcpy(&v, &b, 1); r[i] = (float)v;
    }
    return make_float4(r[0], r[1], r[2], r[3]);
#endif
}

// ---------------- CSR build pass 1: bin packed edges into fixed-CAP dst buckets ----------------
__global__ __launch_bounds__(256) void k_bucket1(const int* __restrict__ src,
                                                 const int* __restrict__ dst,
                                                 int* __restrict__ bcnt,
                                                 unsigned int* __restrict__ staging) {
    __shared__ int hist[NB];
    __shared__ int base[NB];
    int tid = threadIdx.x;
    int chunk0 = blockIdx.x * 8192;
    if (tid < NB) hist[tid] = 0;
    __syncthreads();
    for (int i = tid; i < 8192; i += 256) {
        int e = chunk0 + i;
        if (e < NE) atomicAdd(&hist[dst[e] >> 10], 1);
    }
    __syncthreads();
    if (tid < NB) { base[tid] = atomicAdd(&bcnt[tid], hist[tid]); hist[tid] = 0; }
    __syncthreads();
    for (int i = tid; i < 8192; i += 256) {
        int e = chunk0 + i;
        if (e < NE) {
            int d = dst[e];
            int bk = d >> 10;
            int off = base[bk] + atomicAdd(&hist[bk], 1);
            if (off < CAP)
                staging[(size_t)bk * CAP + off] = ((unsigned)src[e] << 10) | (unsigned)(d & 1023);
        }
    }
}

// ---------------- bucket prefix (block 0) + graph boundaries (block 1) ----------------
__global__ void k_bprefix(const int* __restrict__ bcnt, int* __restrict__ bbase,
                          int* __restrict__ rowptr,
                          const int* __restrict__ batch, int* __restrict__ gstart) {
    if (blockIdx.x == 0) {
        if (threadIdx.x == 0) {
            int run = 0;
            for (int i = 0; i < NB; i++) { bbase[i] = run; run += bcnt[i]; }
            rowptr[NN] = NE;
        }
    } else {
        int g = threadIdx.x;
        if (g > NG) return;
        if (g == NG) { gstart[g] = NN; return; }
        int lo = 0, hi = NN;
        while (lo < hi) { int mid = (lo + hi) >> 1; if (batch[mid] < g) lo = mid + 1; else hi = mid; }
        gstart[g] = lo;
    }
}

// ---------------- CSR build pass 2: per-bucket deg/rowptr/dis + col scatter in LDS ----------------
__global__ __launch_bounds__(256) void k_bucket2(const unsigned int* __restrict__ staging,
                                                 const int* __restrict__ bcnt,
                                                 const int* __restrict__ bbase,
                                                 int* __restrict__ rowptr,
                                                 float* __restrict__ dis,
                                                 int* __restrict__ col) {
    __shared__ int degl[1024];
    __shared__ int cur[1024];
    __shared__ int tsum[256];
    int b = blockIdx.x, tid = threadIdx.x;
    int n0 = b << 10;
    int cnt = bcnt[b];
    int base = bbase[b];
    const unsigned int* st = staging + (size_t)b * CAP;
    ((int4*)degl)[tid] = make_int4(0, 0, 0, 0);
    __syncthreads();
    for (int i = tid; i < cnt; i += 256) atomicAdd(&degl[st[i] & 1023], 1);
    __syncthreads();
    int v[4], s = 0;
    #pragma unroll
    for (int k = 0; k < 4; k++) { v[k] = degl[tid * 4 + k]; s += v[k]; }
    tsum[tid] = s;
    __syncthreads();
    for (int off = 1; off < 256; off <<= 1) {
        int t = (tid >= off) ? tsum[tid - off] : 0;
        __syncthreads();
        tsum[tid] += t;
        __syncthreads();
    }
    int run = (tid == 0) ? 0 : tsum[tid - 1];
    #pragma unroll
    for (int k = 0; k < 4; k++) {
        int i = tid * 4 + k, node = n0 + i;
        if (node < NN) {
            rowptr[node] = base + run;
            cur[i] = run;
            dis[node] = rsqrtf((float)v[k] + 1.0f);
        }
        run += v[k];
    }
    __syncthreads();
    for (int i = tid; i < cnt; i += 256) {
        unsigned int e = st[i];
        int pos = atomicAdd(&cur[e & 1023], 1);
        col[base + pos] = (int)(e >> 10);
    }
}

// ---------------- W -> Wt (transposed, f16, PERMUTED rows), one dispatch ----------------
// Permuted so MFMA tile nt, lane m computes original column c = m*8+nt:
// Wt row n' holds original W column ((n'&15)*8 + (n'>>4)).
__global__ void k_prepw3(const float* __restrict__ W0, const float* __restrict__ W1,
                         const float* __restrict__ W2, _Float16* __restrict__ Wt) {
    int gi = blockIdx.x * 256 + threadIdx.x;  // 3 * 16384
    int l = gi >> 14, idx = gi & 16383;
    const float* W = (l == 0) ? W0 : (l == 1) ? W1 : W2;
    int n = idx >> 7, k = idx & 127;
    int c = ((n & 15) << 3) | (n >> 4);
    Wt[gi - idx + (n << 7) + k] = (_Float16)W[k * 128 + c];
}

// ---------------- MFMA GEMM: Y_fp8 = (relu(X*scale+shift) @ W) * dis[row] ----------------
// B-frags read directly from global Wt (32 KB, L1-resident). Epilogue: each lane owns
// cols m*8..m*8+7 -> one 8-byte coalesced fp8 store per row.
__global__ __launch_bounds__(256) void k_gemm(const float* __restrict__ Xf,
                                              const _Float16* __restrict__ Xh,
                                              const float* __restrict__ ss,
                                              const _Float16* __restrict__ Wt,
                                              const float* __restrict__ dis,
                                              unsigned char* __restrict__ Y) {
    __shared__ _Float16 Xl[64][136];
    int tid = threadIdx.x;
    int row0 = blockIdx.x * 64;

    if (Xh) {
        #pragma unroll
        for (int p = 0; p < 4; p++) {
            int idx = p * 2048 + tid * 8;
            int r = idx >> 7, c = idx & 127;
            int gr = row0 + r;
            half8 hv = {};
            if (gr < NN) hv = *(const half8*)&Xh[(size_t)gr * H + c];
            float4 sc0 = ((const float4*)ss)[c >> 2];
            float4 sc1 = ((const float4*)ss)[(c >> 2) + 1];
            float4 sh0 = ((const float4*)(ss + 128))[c >> 2];
            float4 sh1 = ((const float4*)(ss + 128))[(c >> 2) + 1];
            half8 o;
            o[0] = (_Float16)fmaxf((float)hv[0] * sc0.x + sh0.x, 0.f);
            o[1] = (_Float16)fmaxf((float)hv[1] * sc0.y + sh0.y, 0.f);
            o[2] = (_Float16)fmaxf((float)hv[2] * sc0.z + sh0.z, 0.f);
            o[3] = (_Float16)fmaxf((float)hv[3] * sc0.w + sh0.w, 0.f);
            o[4] = (_Float16)fmaxf((float)hv[4] * sc1.x + sh1.x, 0.f);
            o[5] = (_Float16)fmaxf((float)hv[5] * sc1.y + sh1.y, 0.f);
            o[6] = (_Float16)fmaxf((float)hv[6] * sc1.z + sh1.z, 0.f);
            o[7] = (_Float16)fmaxf((float)hv[7] * sc1.w + sh1.w, 0.f);
            *(half8*)&Xl[r][c] = o;
        }
    } else {
        #pragma unroll
        for (int p = 0; p < 8; p++) {
            int idx = p * 1024 + tid * 4;
            int r = idx >> 7, c = idx & 127;
            int gr = row0 + r;
            float4 v = make_float4(0.f, 0.f, 0.f, 0.f);
            if (gr < NN) v = *(const float4*)&Xf[(size_t)gr * H + c];
            half4 hv = {(_Float16)v.x, (_Float16)v.y, (_Float16)v.z, (_Float16)v.w};
            *(half4*)&Xl[r][c] = hv;
        }
    }
    __syncthreads();

    int wave = tid >> 6;
    int lane = tid & 63;
    int m = lane & 15;
    int quad = lane >> 4;

    half8 afrag[4];
    #pragma unroll
    for (int kc = 0; kc < 4; kc++)
        afrag[kc] = *(const half8*)&Xl[wave * 16 + m][kc * 32 + quad * 8];

    f32x4 acc[8];
    #pragma unroll
    for (int nt = 0; nt < 8; nt++) acc[nt] = (f32x4){0.f, 0.f, 0.f, 0.f};

    #pragma unroll
    for (int kc = 0; kc < 4; kc++) {
        #pragma unroll
        for (int nt = 0; nt < 8; nt++) {
            half8 b = *(const half8*)&Wt[(nt * 16 + m) * 128 + kc * 32 + quad * 8];
            acc[nt] = __builtin_amdgcn_mfma_f32_16x16x32_f16(afrag[kc], b, acc[nt], 0, 0, 0);
        }
    }

    #pragma unroll
    for (int r = 0; r < 4; r++) {
        int gr = row0 + wave * 16 + quad * 4 + r;
        if (gr < NN) {
            float dv = dis[gr];
            unsigned int lo = 0, hi = 0;
            #pragma unroll
            for (int nt = 0; nt < 4; nt++)
                lo |= (unsigned int)ftofp8(acc[nt][r] * dv) << (8 * nt);
            #pragma unroll
            for (int nt = 4; nt < 8; nt++)
                hi |= (unsigned int)ftofp8(acc[nt][r] * dv) << (8 * (nt - 4));
            uint2 pk = make_uint2(lo, hi);
            *(uint2*)&Y[(size_t)gr * H + m * 8] = pk;
        }
    }
}

// ---------------- gather aggregate + fused BN stats partials ----------------
// One node per 64-lane wave: 8 feature-lanes x 8 edge sub-streams.
__global__ __launch_bounds__(256) void k_agg(const unsigned char* __restrict__ hs,
                                             const int* __restrict__ rowptr,
                                             const int* __restrict__ col,
                                             const float* __restrict__ dis,
                                             const float* __restrict__ bias,
                                             _Float16* __restrict__ out,
                                             float* __restrict__ sp) {
    int wv = threadIdx.x >> 6;            // 0..3
    int node = blockIdx.x * 4 + wv;
    int lane = threadIdx.x & 63;
    int fl = lane & 7;     // feature slice: feats 16*fl .. 16*fl+15
    int sub = lane >> 3;   // edge sub-stream 0..7
    int beg = rowptr[node], end = rowptr[node + 1];
    float dd = dis[node];
    const uint4* h16 = (const uint4*)hs;  // 8 uint4 per 128B row

    float acc[16];
    #pragma unroll
    for (int k = 0; k < 16; k++) acc[k] = 0.f;
    if (sub == 0) {
        uint4 w = h16[(size_t)node * 8 + fl];
        float4 a0 = fp8x4tof(w.x), a1 = fp8x4tof(w.y), a2 = fp8x4tof(w.z), a3 = fp8x4tof(w.w);
        acc[0] = a0.x; acc[1] = a0.y; acc[2] = a0.z; acc[3] = a0.w;
        acc[4] = a1.x; acc[5] = a1.y; acc[6] = a1.z; acc[7] = a1.w;
        acc[8] = a2.x; acc[9] = a2.y; acc[10] = a2.z; acc[11] = a2.w;
        acc[12] = a3.x; acc[13] = a3.y; acc[14] = a3.z; acc[15] = a3.w;
    }

    #define ACCUM(W) { \
        float4 t0 = fp8x4tof((W).x), t1 = fp8x4tof((W).y), t2 = fp8x4tof((W).z), t3 = fp8x4tof((W).w); \
        acc[0] += t0.x; acc[1] += t0.y; acc[2] += t0.z; acc[3] += t0.w; \
        acc[4] += t1.x; acc[5] += t1.y; acc[6] += t1.z; acc[7] += t1.w; \
        acc[8] += t2.x; acc[9] += t2.y; acc[10] += t2.z; acc[11] += t2.w; \
        acc[12] += t3.x; acc[13] += t3.y; acc[14] += t3.z; acc[15] += t3.w; }

    int j = beg + sub;
    for (; j + 8 < end; j += 16) {
        int c0 = col[j], c1 = col[j + 8];
        uint4 w0 = h16[(size_t)c0 * 8 + fl];
        uint4 w1 = h16[(size_t)c1 * 8 + fl];
        ACCUM(w0) ACCUM(w1)
    }
    for (; j < end; j += 8) {
        uint4 w = h16[(size_t)col[j] * 8 + fl];
        ACCUM(w)
    }
    #undef ACCUM

    // butterfly over the 8 sub-streams (lanes xor 8,16,32)
    #pragma unroll
    for (int k = 0; k < 16; k++) {
        acc[k] += __shfl_xor(acc[k], 8, 64);
        acc[k] += __shfl_xor(acc[k], 16, 64);
        acc[k] += __shfl_xor(acc[k], 32, 64);
    }

    float4 b0 = ((const float4*)bias)[fl * 4 + 0];
    float4 b1 = ((const float4*)bias)[fl * 4 + 1];
    float4 b2 = ((const float4*)bias)[fl * 4 + 2];
    float4 b3 = ((const float4*)bias)[fl * 4 + 3];
    float o[16];
    o[0]  = acc[0]  * dd + b0.x; o[1]  = acc[1]  * dd + b0.y;
    o[2]  = acc[2]  * dd + b0.z; o[3]  = acc[3]  * dd + b0.w;
    o[4]  = acc[4]  * dd + b1.x; o[5]  = acc[5]  * dd + b1.y;
    o[6]  = acc[6]  * dd + b1.z; o[7]  = acc[7]  * dd + b1.w;
    o[8]  = acc[8]  * dd + b2.x; o[9]  = acc[9]  * dd + b2.y;
    o[10] = acc[10] * dd + b2.z; o[11] = acc[11] * dd + b2.w;
    o[12] = acc[12] * dd + b3.x; o[13] = acc[13] * dd + b3.y;
    o[14] = acc[14] * dd + b3.z; o[15] = acc[15] * dd + b3.w;

    __shared__ float lsum[4][128];
    __shared__ float lsq[4][128];
    if (sub == 0) {
        half8 o0, o1;
        #pragma unroll
        for (int k = 0; k < 8; k++) { o0[k] = (_Float16)o[k]; o1[k] = (_Float16)o[k + 8]; }
        half8* orow = (half8*)(out + (size_t)node * H);
        orow[fl * 2] = o0;
        orow[fl * 2 + 1] = o1;
    }
    // stats: all 64 lanes write float2 (lane (fl,sub) -> features fl*16+sub*2, +1)
    {
        int fi = fl * 16 + sub * 2;
        float va = o[sub * 2], vb = o[sub * 2 + 1];
        *(float2*)&lsum[wv][fi] = make_float2(va, vb);
        *(float2*)&lsq[wv][fi] = make_float2(va * va, vb * vb);
    }
    __syncthreads();
    int c = threadIdx.x & 127;
    int which = threadIdx.x >> 7;  // 0 = sum, 1 = sumsq
    float v = 0.f;
    #pragma unroll
    for (int w = 0; w < 4; w++) v += which ? lsq[w][c] : lsum[w][c];
    atomicAdd(&sp[(blockIdx.x & (NSLOT - 1)) * 256 + which * 128 + c], v);
}

// ---------------- BN stats final reduce + scale/shift (re-zeros sp) ----------------
__global__ __launch_bounds__(256) void k_stats_bss(float* __restrict__ sp,
                                                   const float* __restrict__ gamma,
                                                   const float* __restrict__ beta,
                                                   float* __restrict__ ss) {
    __shared__ float sums[256];
    int c = threadIdx.x;  // 256
    float a = 0.f;
    for (int i = 0; i < NSLOT; i++) { a += sp[i * 256 + c]; sp[i * 256 + c] = 0.f; }
    sums[c] = a;
    __syncthreads();
    if (c < 128) {
        float mean = sums[c] * (1.0f / NN);
        float var  = sums[128 + c] * (1.0f / NN) - mean * mean;
        float sc   = gamma[c] * rsqrtf(var + 1e-5f);
        ss[c] = sc;
        ss[128 + c] = beta[c] - mean * sc;
    }
}

// ---------------- fused mean pool (BN+ReLU) + MLP head + log_softmax ----------------
__global__ __launch_bounds__(256) void k_poolhead(const _Float16* __restrict__ x,
                                                  const float* __restrict__ ss,
                                                  const int* __restrict__ gstart,
                                                  const float* __restrict__ w1, const float* __restrict__ b1,
                                                  const float* __restrict__ w2, const float* __restrict__ b2,
                                                  float* __restrict__ out) {
    int g = blockIdx.x;
    int beg = gstart[g], end = gstart[g + 1];
    int lane = threadIdx.x & 31;
    int walker = threadIdx.x >> 5;
    const half4* x4 = (const half4*)x;
    float4 sc = ((const float4*)ss)[lane];
    float4 sh = ((const float4*)(ss + 128))[lane];
    float4 acc = make_float4(0.f, 0.f, 0.f, 0.f);
    for (int r = beg + walker; r < end; r += 8) {
        half4 v = x4[(size_t)r * 32 + lane];
        acc.x += fmaxf((float)v.x * sc.x + sh.x, 0.f);
        acc.y += fmaxf((float)v.y * sc.y + sh.y, 0.f);
        acc.z += fmaxf((float)v.z * sc.z + sh.z, 0.f);
        acc.w += fmaxf((float)v.w * sc.w + sh.w, 0.f);
    }
    __shared__ float4 red[256];
    __shared__ float p[H], hh[H], lg[NC], lsred;
    red[threadIdx.x] = acc;
    __syncthreads();
    if (threadIdx.x < 32) {
        float4 s = red[threadIdx.x];
        for (int w = 1; w < 8; w++) {
            float4 v = red[w * 32 + threadIdx.x];
            s.x += v.x; s.y += v.y; s.z += v.z; s.w += v.w;
        }
        float inv = 1.0f / fmaxf((float)(end - beg), 1.0f);
        ((float4*)p)[threadIdx.x] = make_float4(s.x * inv, s.y * inv, s.z * inv, s.w * inv);
    }
    __syncthreads();
    int f = threadIdx.x;
    if (f < H) {
        float a = b1[f];
        for (int k = 0; k < H; k++) a += p[k] * w1[k * H + f];
        hh[f] = a > 0.f ? a : 0.f;
    }
    __syncthreads();
    if (f < NC) {
        float l = b2[f];
        for (int k = 0; k < H; k++) l += hh[k] * w2[k * NC + f];
        lg[f] = l;
    }
    __syncthreads();
    if (f == 0) {
        float m = lg[0];
        for (int c = 1; c < NC; c++) m = m > lg[c] ? m : lg[c];
        float s = 0.f;
        for (int c = 0; c < NC; c++) s += expf(lg[c] - m);
        lsred = m + logf(s);
    }
    __syncthreads();
    if (f < NC) out[g * NC + f] = lg[f] - lsred;
}

extern "C" void kernel_launch(void* const* d_in, const int* in_sizes, int n_in,
                              void* d_out, int out_size, void* d_ws, size_t ws_size,
                              hipStream_t stream) {
    const float* x     = (const float*)d_in[0];
    const int*   ei    = (const int*)d_in[1];
    const int*   srcp  = ei;
    const int*   dstp  = ei + NE;
    const int*   batch = (const int*)d_in[2];
    const float* W[3]  = {(const float*)d_in[3],  (const float*)d_in[7],  (const float*)d_in[11]};
    const float* b[3]  = {(const float*)d_in[4],  (const float*)d_in[8],  (const float*)d_in[12]};
    const float* gm[3] = {(const float*)d_in[5],  (const float*)d_in[9],  (const float*)d_in[13]};
    const float* bt[3] = {(const float*)d_in[6],  (const float*)d_in[10], (const float*)d_in[14]};
    const float* w1 = (const float*)d_in[15];
    const float* b1 = (const float*)d_in[16];
    const float* w2 = (const float*)d_in[17];
    const float* b2 = (const float*)d_in[18];
    float* out = (float*)d_out;

    float* ws        = (float*)d_ws;
    float* dis       = ws;                          // 100000
    int*   rowptr    = (int*)(ws + 100000);         // 100001 (pad 100004)
    int*   bcnt      = (int*)(ws + 200004);         // 98 (pad 128)
    int*   bbase     = (int*)(ws + 200132);         // 98 (pad 128)
    int*   gstart    = (int*)(ws + 200260);         // 101 (pad 108)
    float* ssbuf     = ws + 200368;                 // 768
    float* sp        = ws + 201136;                 // NSLOT*256 = 65536
    _Float16* wt     = (_Float16*)(ws + 266672);    // 3*16384 halves
    int*   col       = (int*)(ws + 291248);         // NE
    unsigned int* staging = (unsigned int*)(ws + 1891248);  // NB*CAP
    _Float16* aggh   = (_Float16*)(ws + 3697584);   // NN*H f16
    unsigned char* hb = (unsigned char*)(ws + 10097584);  // NN*H fp8

    hipMemsetAsync(bcnt, 0, NB * sizeof(int), stream);
    hipMemsetAsync(sp, 0, NSLOT * 256 * sizeof(float), stream);
    k_bucket1<<<(NE + 8191) / 8192, 256, 0, stream>>>(srcp, dstp, bcnt, staging);
    k_bprefix<<<2, 128, 0, stream>>>(bcnt, bbase, rowptr, batch, gstart);
    k_bucket2<<<NB, 256, 0, stream>>>(staging, bcnt, bbase, rowptr, dis, col);
    k_prepw3<<<192, 256, 0, stream>>>(W[0], W[1], W[2], wt);

    const float* ss_prev = nullptr;
    for (int l = 0; l < 3; l++) {
        float* ss = ssbuf + l * 256;
        k_gemm<<<(NN + 63) / 64, 256, 0, stream>>>(l == 0 ? x : nullptr,
                                                   l == 0 ? nullptr : aggh,
                                                   ss_prev, wt + l * 16384, dis, hb);
        k_agg<<<NN / 4, 256, 0, stream>>>(hb, rowptr, col, dis, b[l], aggh, sp);
        k_stats_bss<<<1, 256, 0, stream>>>(sp, gm[l], bt[l], ss);
        ss_prev = ss;
    }

    k_poolhead<<<NG, 256, 0, stream>>>(aggh, ssbuf + 2 * 256, gstart, w1, b1, w2, b2, out);
}

// Round 13
// 514.830 us; speedup vs baseline: 1.1196x; 1.1196x over previous
//
#include <hip/hip_runtime.h>
#include <hip/hip_fp8.h>
#include <math.h>

constexpr int NN = 100000;   // nodes
constexpr int NE = 1600000;  // edges
constexpr int H  = 128;      // feat/hidden
constexpr int NG = 100;      // graphs
constexpr int NC = 10;       // classes
constexpr int NB = 98;       // CSR buckets (dst >> 10)
constexpr int CAP = 18432;   // per-bucket staging capacity
constexpr int NSLOT = 256;   // BN stats partial slots

typedef _Float16 half8 __attribute__((ext_vector_type(8)));
typedef _Float16 half4 __attribute__((ext_vector_type(4)));
typedef float    f32x4 __attribute__((ext_vector_type(4)));
typedef float    f32x2 __attribute__((ext_vector_type(2)));

// ---- fp8 e4m3 (OCP) helpers ----
static __device__ __forceinline__ unsigned char ftofp8(float f) {
#if __has_builtin(__builtin_amdgcn_cvt_pk_fp8_f32)
    int r = __builtin_amdgcn_cvt_pk_fp8_f32(f, f, 0, false);
    return (unsigned char)(r & 0xff);
#else
    __hip_fp8_e4m3 v(f);
    unsigned char b; __builtin_memcpy(&b, &v, 1); return b;
#endif
}

static __device__ __forceinline__ float4 fp8x4tof(unsigned int u) {
#if __has_builtin(__builtin_amdgcn_cvt_pk_f32_fp8)
    f32x2 lo = __builtin_amdgcn_cvt_pk_f32_fp8(u, false);
    f32x2 hi = __builtin_amdgcn_cvt_pk_f32_fp8(u, true);
    return make_float4(lo.x, lo.y, hi.x, hi.y);
#else
    float r[4];
    #pragma unroll
    for (int i = 0; i < 4; i++) {
        unsigned char b = (u >> (8 * i)) & 0xff;
        __hip_fp8_e4m3 v; __builtin_memcpy(&v, &b, 1); r[i] = (float)v;
    }
    return make_float4(r[0], r[1], r[2], r[3]);
#endif
}

// ---------------- CSR build pass 1: bin packed edges into fixed-CAP dst buckets ----------------
__global__ __launch_bounds__(256) void k_bucket1(const int* __restrict__ src,
                                                 const int* __restrict__ dst,
                                                 int* __restrict__ bcnt,
                                                 unsigned int* __restrict__ staging) {
    __shared__ int hist[NB];
    __shared__ int base[NB];
    int tid = threadIdx.x;
    int chunk0 = blockIdx.x * 8192;
    if (tid < NB) hist[tid] = 0;
    __syncthreads();
    for (int i = tid; i < 8192; i += 256) {
        int e = chunk0 + i;
        if (e < NE) atomicAdd(&hist[dst[e] >> 10], 1);
    }
    __syncthreads();
    if (tid < NB) { base[tid] = atomicAdd(&bcnt[tid], hist[tid]); hist[tid] = 0; }
    __syncthreads();
    for (int i = tid; i < 8192; i += 256) {
        int e = chunk0 + i;
        if (e < NE) {
            int d = dst[e];
            int bk = d >> 10;
            int off = base[bk] + atomicAdd(&hist[bk], 1);
            if (off < CAP)
                staging[(size_t)bk * CAP + off] = ((unsigned)src[e] << 10) | (unsigned)(d & 1023);
        }
    }
}

// ---------------- bucket prefix (block 0) + graph boundaries (block 1) ----------------
__global__ void k_bprefix(const int* __restrict__ bcnt, int* __restrict__ bbase,
                          int* __restrict__ rowptr,
                          const int* __restrict__ batch, int* __restrict__ gstart) {
    if (blockIdx.x == 0) {
        if (threadIdx.x == 0) {
            int run = 0;
            for (int i = 0; i < NB; i++) { bbase[i] = run; run += bcnt[i]; }
            rowptr[NN] = NE;
        }
    } else {
        int g = threadIdx.x;
        if (g > NG) return;
        if (g == NG) { gstart[g] = NN; return; }
        int lo = 0, hi = NN;
        while (lo < hi) { int mid = (lo + hi) >> 1; if (batch[mid] < g) lo = mid + 1; else hi = mid; }
        gstart[g] = lo;
    }
}

// ---------------- CSR build pass 2: per-bucket deg/rowptr/dis + col scatter in LDS ----------------
__global__ __launch_bounds__(256) void k_bucket2(const unsigned int* __restrict__ staging,
                                                 const int* __restrict__ bcnt,
                                                 const int* __restrict__ bbase,
                                                 int* __restrict__ rowptr,
                                                 float* __restrict__ dis,
                                                 int* __restrict__ col) {
    __shared__ int degl[1024];
    __shared__ int cur[1024];
    __shared__ int tsum[256];
    int b = blockIdx.x, tid = threadIdx.x;
    int n0 = b << 10;
    int cnt = bcnt[b];
    int base = bbase[b];
    const unsigned int* st = staging + (size_t)b * CAP;
    ((int4*)degl)[tid] = make_int4(0, 0, 0, 0);
    __syncthreads();
    for (int i = tid; i < cnt; i += 256) atomicAdd(&degl[st[i] & 1023], 1);
    __syncthreads();
    int v[4], s = 0;
    #pragma unroll
    for (int k = 0; k < 4; k++) { v[k] = degl[tid * 4 + k]; s += v[k]; }
    tsum[tid] = s;
    __syncthreads();
    for (int off = 1; off < 256; off <<= 1) {
        int t = (tid >= off) ? tsum[tid - off] : 0;
        __syncthreads();
        tsum[tid] += t;
        __syncthreads();
    }
    int run = (tid == 0) ? 0 : tsum[tid - 1];
    #pragma unroll
    for (int k = 0; k < 4; k++) {
        int i = tid * 4 + k, node = n0 + i;
        if (node < NN) {
            rowptr[node] = base + run;
            cur[i] = run;
            dis[node] = rsqrtf((float)v[k] + 1.0f);
        }
        run += v[k];
    }
    __syncthreads();
    for (int i = tid; i < cnt; i += 256) {
        unsigned int e = st[i];
        int pos = atomicAdd(&cur[e & 1023], 1);
        col[base + pos] = (int)(e >> 10);
    }
}

// ---------------- W -> Wt (transposed, f16, PERMUTED rows), one dispatch ----------------
// Wt row n' holds original W column ((n'&15)*8 + (n'>>4)); MFMA tile nt, lane m
// then computes original column m*8+nt -> contiguous 8-byte epilogue store.
__global__ void k_prepw3(const float* __restrict__ W0, const float* __restrict__ W1,
                         const float* __restrict__ W2, _Float16* __restrict__ Wt) {
    int gi = blockIdx.x * 256 + threadIdx.x;  // 3 * 16384
    int l = gi >> 14, idx = gi & 16383;
    const float* W = (l == 0) ? W0 : (l == 1) ? W1 : W2;
    int n = idx >> 7, k = idx & 127;
    int c = ((n & 15) << 3) | (n >> 4);
    Wt[gi - idx + (n << 7) + k] = (_Float16)W[k * 128 + c];
}

// ---------------- MFMA GEMM: Y_fp8 = (relu(X*scale+shift) @ W) * dis[row] ----------------
// Wl staged in LDS (R11 structure); coalesced uint2 fp8 epilogue (R12 gain).
__global__ __launch_bounds__(256) void k_gemm(const float* __restrict__ Xf,
                                              const _Float16* __restrict__ Xh,
                                              const float* __restrict__ ss,
                                              const _Float16* __restrict__ Wt,
                                              const float* __restrict__ dis,
                                              unsigned char* __restrict__ Y) {
    __shared__ _Float16 Wl[128][136];
    __shared__ _Float16 Xl[64][136];
    int tid = threadIdx.x;
    int row0 = blockIdx.x * 64;

    #pragma unroll
    for (int p = 0; p < 8; p++) {
        int idx = p * 2048 + tid * 8;
        int r = idx >> 7, c = idx & 127;
        *(uint4*)&Wl[r][c] = ((const uint4*)Wt)[idx >> 3];
    }
    if (Xh) {
        #pragma unroll
        for (int p = 0; p < 4; p++) {
            int idx = p * 2048 + tid * 8;
            int r = idx >> 7, c = idx & 127;
            int gr = row0 + r;
            half8 hv = {};
            if (gr < NN) hv = *(const half8*)&Xh[(size_t)gr * H + c];
            float4 sc0 = ((const float4*)ss)[c >> 2];
            float4 sc1 = ((const float4*)ss)[(c >> 2) + 1];
            float4 sh0 = ((const float4*)(ss + 128))[c >> 2];
            float4 sh1 = ((const float4*)(ss + 128))[(c >> 2) + 1];
            half8 o;
            o[0] = (_Float16)fmaxf((float)hv[0] * sc0.x + sh0.x, 0.f);
            o[1] = (_Float16)fmaxf((float)hv[1] * sc0.y + sh0.y, 0.f);
            o[2] = (_Float16)fmaxf((float)hv[2] * sc0.z + sh0.z, 0.f);
            o[3] = (_Float16)fmaxf((float)hv[3] * sc0.w + sh0.w, 0.f);
            o[4] = (_Float16)fmaxf((float)hv[4] * sc1.x + sh1.x, 0.f);
            o[5] = (_Float16)fmaxf((float)hv[5] * sc1.y + sh1.y, 0.f);
            o[6] = (_Float16)fmaxf((float)hv[6] * sc1.z + sh1.z, 0.f);
            o[7] = (_Float16)fmaxf((float)hv[7] * sc1.w + sh1.w, 0.f);
            *(half8*)&Xl[r][c] = o;
        }
    } else {
        #pragma unroll
        for (int p = 0; p < 8; p++) {
            int idx = p * 1024 + tid * 4;
            int r = idx >> 7, c = idx & 127;
            int gr = row0 + r;
            float4 v = make_float4(0.f, 0.f, 0.f, 0.f);
            if (gr < NN) v = *(const float4*)&Xf[(size_t)gr * H + c];
            half4 hv = {(_Float16)v.x, (_Float16)v.y, (_Float16)v.z, (_Float16)v.w};
            *(half4*)&Xl[r][c] = hv;
        }
    }
    __syncthreads();

    int wave = tid >> 6;
    int lane = tid & 63;
    int m = lane & 15;
    int quad = lane >> 4;

    half8 afrag[4];
    #pragma unroll
    for (int kc = 0; kc < 4; kc++)
        afrag[kc] = *(const half8*)&Xl[wave * 16 + m][kc * 32 + quad * 8];

    f32x4 acc[8];
    #pragma unroll
    for (int nt = 0; nt < 8; nt++) acc[nt] = (f32x4){0.f, 0.f, 0.f, 0.f};

    #pragma unroll
    for (int kc = 0; kc < 4; kc++) {
        #pragma unroll
        for (int nt = 0; nt < 8; nt++) {
            half8 b = *(const half8*)&Wl[nt * 16 + m][kc * 32 + quad * 8];
            acc[nt] = __builtin_amdgcn_mfma_f32_16x16x32_f16(afrag[kc], b, acc[nt], 0, 0, 0);
        }
    }

    #pragma unroll
    for (int r = 0; r < 4; r++) {
        int gr = row0 + wave * 16 + quad * 4 + r;
        if (gr < NN) {
            float dv = dis[gr];
            unsigned int lo = 0, hi = 0;
            #pragma unroll
            for (int nt = 0; nt < 4; nt++)
                lo |= (unsigned int)ftofp8(acc[nt][r] * dv) << (8 * nt);
            #pragma unroll
            for (int nt = 4; nt < 8; nt++)
                hi |= (unsigned int)ftofp8(acc[nt][r] * dv) << (8 * (nt - 4));
            uint2 pk = make_uint2(lo, hi);
            *(uint2*)&Y[(size_t)gr * H + m * 8] = pk;
        }
    }
}

// ---------------- gather aggregate + fused BN stats partials ----------------
// One node per 64-lane wave: 8 feature-lanes x 8 edge sub-streams.
__global__ __launch_bounds__(256) void k_agg(const unsigned char* __restrict__ hs,
                                             const int* __restrict__ rowptr,
                                             const int* __restrict__ col,
                                             const float* __restrict__ dis,
                                             const float* __restrict__ bias,
                                             _Float16* __restrict__ out,
                                             float* __restrict__ sp) {
    int wv = threadIdx.x >> 6;            // 0..3
    int node = blockIdx.x * 4 + wv;
    int lane = threadIdx.x & 63;
    int fl = lane & 7;     // feature slice: feats 16*fl .. 16*fl+15
    int sub = lane >> 3;   // edge sub-stream 0..7
    int beg = rowptr[node], end = rowptr[node + 1];
    float dd = dis[node];
    const uint4* h16 = (const uint4*)hs;  // 8 uint4 per 128B row

    float acc[16];
    #pragma unroll
    for (int k = 0; k < 16; k++) acc[k] = 0.f;
    if (sub == 0) {
        uint4 w = h16[(size_t)node * 8 + fl];
        float4 a0 = fp8x4tof(w.x), a1 = fp8x4tof(w.y), a2 = fp8x4tof(w.z), a3 = fp8x4tof(w.w);
        acc[0] = a0.x; acc[1] = a0.y; acc[2] = a0.z; acc[3] = a0.w;
        acc[4] = a1.x; acc[5] = a1.y; acc[6] = a1.z; acc[7] = a1.w;
        acc[8] = a2.x; acc[9] = a2.y; acc[10] = a2.z; acc[11] = a2.w;
        acc[12] = a3.x; acc[13] = a3.y; acc[14] = a3.z; acc[15] = a3.w;
    }

    #define ACCUM(W) { \
        float4 t0 = fp8x4tof((W).x), t1 = fp8x4tof((W).y), t2 = fp8x4tof((W).z), t3 = fp8x4tof((W).w); \
        acc[0] += t0.x; acc[1] += t0.y; acc[2] += t0.z; acc[3] += t0.w; \
        acc[4] += t1.x; acc[5] += t1.y; acc[6] += t1.z; acc[7] += t1.w; \
        acc[8] += t2.x; acc[9] += t2.y; acc[10] += t2.z; acc[11] += t2.w; \
        acc[12] += t3.x; acc[13] += t3.y; acc[14] += t3.z; acc[15] += t3.w; }

    int j = beg + sub;
    for (; j + 8 < end; j += 16) {
        int c0 = col[j], c1 = col[j + 8];
        uint4 w0 = h16[(size_t)c0 * 8 + fl];
        uint4 w1 = h16[(size_t)c1 * 8 + fl];
        ACCUM(w0) ACCUM(w1)
    }
    for (; j < end; j += 8) {
        uint4 w = h16[(size_t)col[j] * 8 + fl];
        ACCUM(w)
    }
    #undef ACCUM

    // butterfly over the 8 sub-streams (lanes xor 8,16,32)
    #pragma unroll
    for (int k = 0; k < 16; k++) {
        acc[k] += __shfl_xor(acc[k], 8, 64);
        acc[k] += __shfl_xor(acc[k], 16, 64);
        acc[k] += __shfl_xor(acc[k], 32, 64);
    }

    float4 b0 = ((const float4*)bias)[fl * 4 + 0];
    float4 b1 = ((const float4*)bias)[fl * 4 + 1];
    float4 b2 = ((const float4*)bias)[fl * 4 + 2];
    float4 b3 = ((const float4*)bias)[fl * 4 + 3];
    float o[16];
    o[0]  = acc[0]  * dd + b0.x; o[1]  = acc[1]  * dd + b0.y;
    o[2]  = acc[2]  * dd + b0.z; o[3]  = acc[3]  * dd + b0.w;
    o[4]  = acc[4]  * dd + b1.x; o[5]  = acc[5]  * dd + b1.y;
    o[6]  = acc[6]  * dd + b1.z; o[7]  = acc[7]  * dd + b1.w;
    o[8]  = acc[8]  * dd + b2.x; o[9]  = acc[9]  * dd + b2.y;
    o[10] = acc[10] * dd + b2.z; o[11] = acc[11] * dd + b2.w;
    o[12] = acc[12] * dd + b3.x; o[13] = acc[13] * dd + b3.y;
    o[14] = acc[14] * dd + b3.z; o[15] = acc[15] * dd + b3.w;

    __shared__ float lsum[4][128];
    __shared__ float lsq[4][128];
    if (sub == 0) {
        half8 o0, o1;
        #pragma unroll
        for (int k = 0; k < 8; k++) { o0[k] = (_Float16)o[k]; o1[k] = (_Float16)o[k + 8]; }
        half8* orow = (half8*)(out + (size_t)node * H);
        orow[fl * 2] = o0;
        orow[fl * 2 + 1] = o1;
    }
    {
        int fi = fl * 16 + sub * 2;
        float va = o[sub * 2], vb = o[sub * 2 + 1];
        *(float2*)&lsum[wv][fi] = make_float2(va, vb);
        *(float2*)&lsq[wv][fi] = make_float2(va * va, vb * vb);
    }
    __syncthreads();
    int c = threadIdx.x & 127;
    int which = threadIdx.x >> 7;  // 0 = sum, 1 = sumsq
    float v = 0.f;
    #pragma unroll
    for (int w = 0; w < 4; w++) v += which ? lsq[w][c] : lsum[w][c];
    atomicAdd(&sp[(blockIdx.x & (NSLOT - 1)) * 256 + which * 128 + c], v);
}

// ---------------- BN stats final reduce + scale/shift (re-zeros sp) ----------------
__global__ __launch_bounds__(256) void k_stats_bss(float* __restrict__ sp,
                                                   const float* __restrict__ gamma,
                                                   const float* __restrict__ beta,
                                                   float* __restrict__ ss) {
    __shared__ float sums[256];
    int c = threadIdx.x;  // 256
    float a = 0.f;
    for (int i = 0; i < NSLOT; i++) { a += sp[i * 256 + c]; sp[i * 256 + c] = 0.f; }
    sums[c] = a;
    __syncthreads();
    if (c < 128) {
        float mean = sums[c] * (1.0f / NN);
        float var  = sums[128 + c] * (1.0f / NN) - mean * mean;
        float sc   = gamma[c] * rsqrtf(var + 1e-5f);
        ss[c] = sc;
        ss[128 + c] = beta[c] - mean * sc;
    }
}

// ---------------- fused mean pool (BN+ReLU) + MLP head + log_softmax ----------------
__global__ __launch_bounds__(256) void k_poolhead(const _Float16* __restrict__ x,
                                                  const float* __restrict__ ss,
                                                  const int* __restrict__ gstart,
                                                  const float* __restrict__ w1, const float* __restrict__ b1,
                                                  const float* __restrict__ w2, const float* __restrict__ b2,
                                                  float* __restrict__ out) {
    int g = blockIdx.x;
    int beg = gstart[g], end = gstart[g + 1];
    int lane = threadIdx.x & 31;
    int walker = threadIdx.x >> 5;
    const half4* x4 = (const half4*)x;
    float4 sc = ((const float4*)ss)[lane];
    float4 sh = ((const float4*)(ss + 128))[lane];
    float4 acc = make_float4(0.f, 0.f, 0.f, 0.f);
    for (int r = beg + walker; r < end; r += 8) {
        half4 v = x4[(size_t)r * 32 + lane];
        acc.x += fmaxf((float)v.x * sc.x + sh.x, 0.f);
        acc.y += fmaxf((float)v.y * sc.y + sh.y, 0.f);
        acc.z += fmaxf((float)v.z * sc.z + sh.z, 0.f);
        acc.w += fmaxf((float)v.w * sc.w + sh.w, 0.f);
    }
    __shared__ float4 red[256];
    __shared__ float p[H], hh[H], lg[NC], lsred;
    red[threadIdx.x] = acc;
    __syncthreads();
    if (threadIdx.x < 32) {
        float4 s = red[threadIdx.x];
        for (int w = 1; w < 8; w++) {
            float4 v = red[w * 32 + threadIdx.x];
            s.x += v.x; s.y += v.y; s.z += v.z; s.w += v.w;
        }
        float inv = 1.0f / fmaxf((float)(end - beg), 1.0f);
        ((float4*)p)[threadIdx.x] = make_float4(s.x * inv, s.y * inv, s.z * inv, s.w * inv);
    }
    __syncthreads();
    int f = threadIdx.x;
    if (f < H) {
        float a = b1[f];
        for (int k = 0; k < H; k++) a += p[k] * w1[k * H + f];
        hh[f] = a > 0.f ? a : 0.f;
    }
    __syncthreads();
    if (f < NC) {
        float l = b2[f];
        for (int k = 0; k < H; k++) l += hh[k] * w2[k * NC + f];
        lg[f] = l;
    }
    __syncthreads();
    if (f == 0) {
        float m = lg[0];
        for (int c = 1; c < NC; c++) m = m > lg[c] ? m : lg[c];
        float s = 0.f;
        for (int c = 0; c < NC; c++) s += expf(lg[c] - m);
        lsred = m + logf(s);
    }
    __syncthreads();
    if (f < NC) out[g * NC + f] = lg[f] - lsred;
}

extern "C" void kernel_launch(void* const* d_in, const int* in_sizes, int n_in,
                              void* d_out, int out_size, void* d_ws, size_t ws_size,
                              hipStream_t stream) {
    const float* x     = (const float*)d_in[0];
    const int*   ei    = (const int*)d_in[1];
    const int*   srcp  = ei;
    const int*   dstp  = ei + NE;
    const int*   batch = (const int*)d_in[2];
    const float* W[3]  = {(const float*)d_in[3],  (const float*)d_in[7],  (const float*)d_in[11]};
    const float* b[3]  = {(const float*)d_in[4],  (const float*)d_in[8],  (const float*)d_in[12]};
    const float* gm[3] = {(const float*)d_in[5],  (const float*)d_in[9],  (const float*)d_in[13]};
    const float* bt[3] = {(const float*)d_in[6],  (const float*)d_in[10], (const float*)d_in[14]};
    const float* w1 = (const float*)d_in[15];
    const float* b1 = (const float*)d_in[16];
    const float* w2 = (const float*)d_in[17];
    const float* b2 = (const float*)d_in[18];
    float* out = (float*)d_out;

    float* ws        = (float*)d_ws;
    float* dis       = ws;                          // 100000
    int*   rowptr    = (int*)(ws + 100000);         // 100001 (pad 100004)
    int*   bcnt      = (int*)(ws + 200004);         // 98 (pad 128)
    int*   bbase     = (int*)(ws + 200132);         // 98 (pad 128)
    int*   gstart    = (int*)(ws + 200260);         // 101 (pad 108)
    float* ssbuf     = ws + 200368;                 // 768
    float* sp        = ws + 201136;                 // NSLOT*256 = 65536
    _Float16* wt     = (_Float16*)(ws + 266672);    // 3*16384 halves
    int*   col       = (int*)(ws + 291248);         // NE
    unsigned int* staging = (unsigned int*)(ws + 1891248);  // NB*CAP
    _Float16* aggh   = (_Float16*)(ws + 3697584);   // NN*H f16
    unsigned char* hb = (unsigned char*)(ws + 10097584);  // NN*H fp8

    hipMemsetAsync(bcnt, 0, NB * sizeof(int), stream);
    hipMemsetAsync(sp, 0, NSLOT * 256 * sizeof(float), stream);
    k_bucket1<<<(NE + 8191) / 8192, 256, 0, stream>>>(srcp, dstp, bcnt, staging);
    k_bprefix<<<2, 128, 0, stream>>>(bcnt, bbase, rowptr, batch, gstart);
    k_bucket2<<<NB, 256, 0, stream>>>(staging, bcnt, bbase, rowptr, dis, col);
    k_prepw3<<<192, 256, 0, stream>>>(W[0], W[1], W[2], wt);

    const float* ss_prev = nullptr;
    for (int l = 0; l < 3; l++) {
        float* ss = ssbuf + l * 256;
        k_gemm<<<(NN + 63) / 64, 256, 0, stream>>>(l == 0 ? x : nullptr,
                                                   l == 0 ? nullptr : aggh,
                                                   ss_prev, wt + l * 16384, dis, hb);
        k_agg<<<NN / 4, 256, 0, stream>>>(hb, rowptr, col, dis, b[l], aggh, sp);
        k_stats_bss<<<1, 256, 0, stream>>>(sp, gm[l], bt[l], ss);
        ss_prev = ss;
    }

    k_poolhead<<<NG, 256, 0, stream>>>(aggh, ssbuf + 2 * 256, gstart, w1, b1, w2, b2, out);
}

// Round 15
// 508.619 us; speedup vs baseline: 1.1333x; 1.0122x over previous
//
#include <hip/hip_runtime.h>
#include <hip/hip_fp8.h>
#include <math.h>

constexpr int NN = 100000;   // nodes
constexpr int NE = 1600000;  // edges
constexpr int H  = 128;      // feat/hidden
constexpr int NG = 100;      // graphs
constexpr int NC = 10;       // classes
constexpr int NB = 98;       // CSR buckets (dst >> 10)
constexpr int CAP = 18432;   // per-bucket staging capacity
constexpr int NSLOT = 256;   // BN stats partial slots

typedef _Float16 half8 __attribute__((ext_vector_type(8)));
typedef _Float16 half4 __attribute__((ext_vector_type(4)));
typedef float    f32x4 __attribute__((ext_vector_type(4)));
typedef float    f32x2 __attribute__((ext_vector_type(2)));

// ---- fp8 e4m3 (OCP) helpers ----
static __device__ __forceinline__ unsigned char ftofp8(float f) {
#if __has_builtin(__builtin_amdgcn_cvt_pk_fp8_f32)
    int r = __builtin_amdgcn_cvt_pk_fp8_f32(f, f, 0, false);
    return (unsigned char)(r & 0xff);
#else
    __hip_fp8_e4m3 v(f);
    unsigned char b; __builtin_memcpy(&b, &v, 1); return b;
#endif
}

template <bool HI>
static __device__ __forceinline__ f32x2 fp8x2tof(unsigned int u) {
#if __has_builtin(__builtin_amdgcn_cvt_pk_f32_fp8)
    return __builtin_amdgcn_cvt_pk_f32_fp8(u, HI);  // HI is a constant here
#else
    f32x2 r;
    #pragma unroll
    for (int i = 0; i < 2; i++) {
        unsigned char b = (u >> (8 * (i + (HI ? 2 : 0)))) & 0xff;
        __hip_fp8_e4m3 v; __builtin_memcpy(&v, &b, 1); r[i] = (float)v;
    }
    return r;
#endif
}

// ---------------- CSR build pass 1: bin packed edges into fixed-CAP dst buckets ----------------
__global__ __launch_bounds__(256) void k_bucket1(const int* __restrict__ src,
                                                 const int* __restrict__ dst,
                                                 int* __restrict__ bcnt,
                                                 unsigned int* __restrict__ staging) {
    __shared__ int hist[NB];
    __shared__ int base[NB];
    int tid = threadIdx.x;
    int chunk0 = blockIdx.x * 8192;
    if (tid < NB) hist[tid] = 0;
    __syncthreads();
    for (int i = tid; i < 8192; i += 256) {
        int e = chunk0 + i;
        if (e < NE) atomicAdd(&hist[dst[e] >> 10], 1);
    }
    __syncthreads();
    if (tid < NB) { base[tid] = atomicAdd(&bcnt[tid], hist[tid]); hist[tid] = 0; }
    __syncthreads();
    for (int i = tid; i < 8192; i += 256) {
        int e = chunk0 + i;
        if (e < NE) {
            int d = dst[e];
            int bk = d >> 10;
            int off = base[bk] + atomicAdd(&hist[bk], 1);
            if (off < CAP)
                staging[(size_t)bk * CAP + off] = ((unsigned)src[e] << 10) | (unsigned)(d & 1023);
        }
    }
}

// ---------------- bucket prefix (block 0) + graph boundaries (block 1) ----------------
__global__ void k_bprefix(const int* __restrict__ bcnt, int* __restrict__ bbase,
                          int* __restrict__ rowptr,
                          const int* __restrict__ batch, int* __restrict__ gstart) {
    if (blockIdx.x == 0) {
        if (threadIdx.x == 0) {
            int run = 0;
            for (int i = 0; i < NB; i++) { bbase[i] = run; run += bcnt[i]; }
            rowptr[NN] = NE;
        }
    } else {
        int g = threadIdx.x;
        if (g > NG) return;
        if (g == NG) { gstart[g] = NN; return; }
        int lo = 0, hi = NN;
        while (lo < hi) { int mid = (lo + hi) >> 1; if (batch[mid] < g) lo = mid + 1; else hi = mid; }
        gstart[g] = lo;
    }
}

// ---------------- CSR build pass 2: per-bucket deg/rowptr/dis + col scatter in LDS ----------------
__global__ __launch_bounds__(256) void k_bucket2(const unsigned int* __restrict__ staging,
                                                 const int* __restrict__ bcnt,
                                                 const int* __restrict__ bbase,
                                                 int* __restrict__ rowptr,
                                                 float* __restrict__ dis,
                                                 int* __restrict__ col) {
    __shared__ int degl[1024];
    __shared__ int cur[1024];
    __shared__ int tsum[256];
    int b = blockIdx.x, tid = threadIdx.x;
    int n0 = b << 10;
    int cnt = bcnt[b];
    int base = bbase[b];
    const unsigned int* st = staging + (size_t)b * CAP;
    ((int4*)degl)[tid] = make_int4(0, 0, 0, 0);
    __syncthreads();
    for (int i = tid; i < cnt; i += 256) atomicAdd(&degl[st[i] & 1023], 1);
    __syncthreads();
    int v[4], s = 0;
    #pragma unroll
    for (int k = 0; k < 4; k++) { v[k] = degl[tid * 4 + k]; s += v[k]; }
    tsum[tid] = s;
    __syncthreads();
    for (int off = 1; off < 256; off <<= 1) {
        int t = (tid >= off) ? tsum[tid - off] : 0;
        __syncthreads();
        tsum[tid] += t;
        __syncthreads();
    }
    int run = (tid == 0) ? 0 : tsum[tid - 1];
    #pragma unroll
    for (int k = 0; k < 4; k++) {
        int i = tid * 4 + k, node = n0 + i;
        if (node < NN) {
            rowptr[node] = base + run;
            cur[i] = run;
            dis[node] = rsqrtf((float)v[k] + 1.0f);
        }
        run += v[k];
    }
    __syncthreads();
    for (int i = tid; i < cnt; i += 256) {
        unsigned int e = st[i];
        int pos = atomicAdd(&cur[e & 1023], 1);
        col[base + pos] = (int)(e >> 10);
    }
}

// ---------------- W -> Wt (transposed, f16, PERMUTED rows), one dispatch ----------------
__global__ void k_prepw3(const float* __restrict__ W0, const float* __restrict__ W1,
                         const float* __restrict__ W2, _Float16* __restrict__ Wt) {
    int gi = blockIdx.x * 256 + threadIdx.x;  // 3 * 16384
    int l = gi >> 14, idx = gi & 16383;
    const float* W = (l == 0) ? W0 : (l == 1) ? W1 : W2;
    int n = idx >> 7, k = idx & 127;
    int c = ((n & 15) << 3) | (n >> 4);
    Wt[gi - idx + (n << 7) + k] = (_Float16)W[k * 128 + c];
}

// ---------------- MFMA GEMM v2: persistent W in LDS, waves free-run over 16-row tiles ----------------
// Y_fp8 = (relu(X*scale+shift) @ W) * dis[row]. A-frags loaded direct from global
// (layout row=m, k=kc*32+quad*8), BN fused in registers. One barrier total.
__global__ __launch_bounds__(256) void k_gemm(const float* __restrict__ Xf,
                                              const _Float16* __restrict__ Xh,
                                              const float* __restrict__ ss,
                                              const _Float16* __restrict__ Wt,
                                              const float* __restrict__ dis,
                                              unsigned char* __restrict__ Y) {
    __shared__ _Float16 Wl[128][136];
    int tid = threadIdx.x;
    #pragma unroll
    for (int p = 0; p < 8; p++) {
        int idx = p * 2048 + tid * 8;
        int r = idx >> 7, c = idx & 127;
        *(uint4*)&Wl[r][c] = ((const uint4*)Wt)[idx >> 3];
    }
    __syncthreads();

    int lane = tid & 63;
    int m = lane & 15;
    int quad = lane >> 4;
    const int NT = (NN + 15) / 16;          // 6250 tiles
    const int NW = gridDim.x * 4;           // total waves

    for (int t = blockIdx.x * 4 + (tid >> 6); t < NT; t += NW) {
        int row = t * 16 + m;
        bool ok = row < NN;
        half8 afrag[4];
        if (Xh) {
            #pragma unroll
            for (int kc = 0; kc < 4; kc++) {
                int k0 = kc * 32 + quad * 8;
                half8 hv = {};
                if (ok) hv = *(const half8*)&Xh[(size_t)row * H + k0];
                float4 sc0 = ((const float4*)ss)[k0 >> 2];
                float4 sc1 = ((const float4*)ss)[(k0 >> 2) + 1];
                float4 sh0 = ((const float4*)(ss + 128))[k0 >> 2];
                float4 sh1 = ((const float4*)(ss + 128))[(k0 >> 2) + 1];
                half8 o;
                o[0] = (_Float16)fmaxf((float)hv[0] * sc0.x + sh0.x, 0.f);
                o[1] = (_Float16)fmaxf((float)hv[1] * sc0.y + sh0.y, 0.f);
                o[2] = (_Float16)fmaxf((float)hv[2] * sc0.z + sh0.z, 0.f);
                o[3] = (_Float16)fmaxf((float)hv[3] * sc0.w + sh0.w, 0.f);
                o[4] = (_Float16)fmaxf((float)hv[4] * sc1.x + sh1.x, 0.f);
                o[5] = (_Float16)fmaxf((float)hv[5] * sc1.y + sh1.y, 0.f);
                o[6] = (_Float16)fmaxf((float)hv[6] * sc1.z + sh1.z, 0.f);
                o[7] = (_Float16)fmaxf((float)hv[7] * sc1.w + sh1.w, 0.f);
                afrag[kc] = o;
            }
        } else {
            #pragma unroll
            for (int kc = 0; kc < 4; kc++) {
                int k0 = kc * 32 + quad * 8;
                float4 v0 = make_float4(0.f, 0.f, 0.f, 0.f);
                float4 v1 = make_float4(0.f, 0.f, 0.f, 0.f);
                if (ok) {
                    v0 = *(const float4*)&Xf[(size_t)row * H + k0];
                    v1 = *(const float4*)&Xf[(size_t)row * H + k0 + 4];
                }
                half8 o = {(_Float16)v0.x, (_Float16)v0.y, (_Float16)v0.z, (_Float16)v0.w,
                           (_Float16)v1.x, (_Float16)v1.y, (_Float16)v1.z, (_Float16)v1.w};
                afrag[kc] = o;
            }
        }

        f32x4 acc[8];
        #pragma unroll
        for (int nt = 0; nt < 8; nt++) acc[nt] = (f32x4){0.f, 0.f, 0.f, 0.f};
        #pragma unroll
        for (int kc = 0; kc < 4; kc++) {
            #pragma unroll
            for (int nt = 0; nt < 8; nt++) {
                half8 b = *(const half8*)&Wl[nt * 16 + m][kc * 32 + quad * 8];
                acc[nt] = __builtin_amdgcn_mfma_f32_16x16x32_f16(afrag[kc], b, acc[nt], 0, 0, 0);
            }
        }

        #pragma unroll
        for (int r = 0; r < 4; r++) {
            int gr = t * 16 + quad * 4 + r;
            if (gr < NN) {
                float dv = dis[gr];
                unsigned int lo = 0, hi = 0;
                #pragma unroll
                for (int nt = 0; nt < 4; nt++)
                    lo |= (unsigned int)ftofp8(acc[nt][r] * dv) << (8 * nt);
                #pragma unroll
                for (int nt = 4; nt < 8; nt++)
                    hi |= (unsigned int)ftofp8(acc[nt][r] * dv) << (8 * (nt - 4));
                uint2 pk = make_uint2(lo, hi);
                *(uint2*)&Y[(size_t)gr * H + m * 8] = pk;
            }
        }
    }
}

// ---------------- gather aggregate + fused BN stats partials ----------------
// One node per 64-lane wave: 8 feature-lanes x 8 edge sub-streams; f32x2 packed adds.
__global__ __launch_bounds__(256) void k_agg(const unsigned char* __restrict__ hs,
                                             const int* __restrict__ rowptr,
                                             const int* __restrict__ col,
                                             const float* __restrict__ dis,
                                             const float* __restrict__ bias,
                                             _Float16* __restrict__ out,
                                             float* __restrict__ sp) {
    int wv = threadIdx.x >> 6;            // 0..3
    int node = blockIdx.x * 4 + wv;
    int lane = threadIdx.x & 63;
    int fl = lane & 7;     // feature slice: feats 16*fl .. 16*fl+15
    int sub = lane >> 3;   // edge sub-stream 0..7
    int beg = rowptr[node], end = rowptr[node + 1];
    float dd = dis[node];
    const uint4* h16 = (const uint4*)hs;  // 8 uint4 per 128B row

    f32x2 acc2[8];
    #pragma unroll
    for (int k = 0; k < 8; k++) acc2[k] = (f32x2){0.f, 0.f};
    if (sub == 0) {
        uint4 w = h16[(size_t)node * 8 + fl];
        acc2[0] = fp8x2tof<false>(w.x); acc2[1] = fp8x2tof<true>(w.x);
        acc2[2] = fp8x2tof<false>(w.y); acc2[3] = fp8x2tof<true>(w.y);
        acc2[4] = fp8x2tof<false>(w.z); acc2[5] = fp8x2tof<true>(w.z);
        acc2[6] = fp8x2tof<false>(w.w); acc2[7] = fp8x2tof<true>(w.w);
    }

    #define ACCUM(W) { \
        acc2[0] += fp8x2tof<false>((W).x); acc2[1] += fp8x2tof<true>((W).x); \
        acc2[2] += fp8x2tof<false>((W).y); acc2[3] += fp8x2tof<true>((W).y); \
        acc2[4] += fp8x2tof<false>((W).z); acc2[5] += fp8x2tof<true>((W).z); \
        acc2[6] += fp8x2tof<false>((W).w); acc2[7] += fp8x2tof<true>((W).w); }

    int j = beg + sub;
    for (; j + 8 < end; j += 16) {
        int c0 = col[j], c1 = col[j + 8];
        uint4 w0 = h16[(size_t)c0 * 8 + fl];
        uint4 w1 = h16[(size_t)c1 * 8 + fl];
        ACCUM(w0) ACCUM(w1)
    }
    for (; j < end; j += 8) {
        uint4 w = h16[(size_t)col[j] * 8 + fl];
        ACCUM(w)
    }
    #undef ACCUM

    // butterfly over the 8 sub-streams (lanes xor 8,16,32)
    #pragma unroll
    for (int k = 0; k < 8; k++) {
        #pragma unroll
        for (int c = 0; c < 2; c++) {
            acc2[k][c] += __shfl_xor(acc2[k][c], 8, 64);
            acc2[k][c] += __shfl_xor(acc2[k][c], 16, 64);
            acc2[k][c] += __shfl_xor(acc2[k][c], 32, 64);
        }
    }

    float o[16];
    #pragma unroll
    for (int k = 0; k < 8; k++) { o[k * 2] = acc2[k][0]; o[k * 2 + 1] = acc2[k][1]; }
    float4 b0 = ((const float4*)bias)[fl * 4 + 0];
    float4 b1 = ((const float4*)bias)[fl * 4 + 1];
    float4 b2 = ((const float4*)bias)[fl * 4 + 2];
    float4 b3 = ((const float4*)bias)[fl * 4 + 3];
    o[0]  = o[0]  * dd + b0.x; o[1]  = o[1]  * dd + b0.y;
    o[2]  = o[2]  * dd + b0.z; o[3]  = o[3]  * dd + b0.w;
    o[4]  = o[4]  * dd + b1.x; o[5]  = o[5]  * dd + b1.y;
    o[6]  = o[6]  * dd + b1.z; o[7]  = o[7]  * dd + b1.w;
    o[8]  = o[8]  * dd + b2.x; o[9]  = o[9]  * dd + b2.y;
    o[10] = o[10] * dd + b2.z; o[11] = o[11] * dd + b2.w;
    o[12] = o[12] * dd + b3.x; o[13] = o[13] * dd + b3.y;
    o[14] = o[14] * dd + b3.z; o[15] = o[15] * dd + b3.w;

    __shared__ float lsum[4][128];
    __shared__ float lsq[4][128];
    if (sub == 0) {
        half8 o0, o1;
        #pragma unroll
        for (int k = 0; k < 8; k++) { o0[k] = (_Float16)o[k]; o1[k] = (_Float16)o[k + 8]; }
        half8* orow = (half8*)(out + (size_t)node * H);
        orow[fl * 2] = o0;
        orow[fl * 2 + 1] = o1;
    }
    {
        int fi = fl * 16 + sub * 2;
        float va = o[sub * 2], vb = o[sub * 2 + 1];
        *(float2*)&lsum[wv][fi] = make_float2(va, vb);
        *(float2*)&lsq[wv][fi] = make_float2(va * va, vb * vb);
    }
    __syncthreads();
    int c = threadIdx.x & 127;
    int which = threadIdx.x >> 7;  // 0 = sum, 1 = sumsq
    float v = 0.f;
    #pragma unroll
    for (int w = 0; w < 4; w++) v += which ? lsq[w][c] : lsum[w][c];
    atomicAdd(&sp[(blockIdx.x & (NSLOT - 1)) * 256 + which * 128 + c], v);
}

// ---------------- BN stats final reduce + scale/shift (re-zeros sp) ----------------
__global__ __launch_bounds__(256) void k_stats_bss(float* __restrict__ sp,
                                                   const float* __restrict__ gamma,
                                                   const float* __restrict__ beta,
                                                   float* __restrict__ ss) {
    __shared__ float sums[256];
    int c = threadIdx.x;  // 256
    float a = 0.f;
    for (int i = 0; i < NSLOT; i++) { a += sp[i * 256 + c]; sp[i * 256 + c] = 0.f; }
    sums[c] = a;
    __syncthreads();
    if (c < 128) {
        float mean = sums[c] * (1.0f / NN);
        float var  = sums[128 + c] * (1.0f / NN) - mean * mean;
        float sc   = gamma[c] * rsqrtf(var + 1e-5f);
        ss[c] = sc;
        ss[128 + c] = beta[c] - mean * sc;
    }
}

// ---------------- fused mean pool (BN+ReLU) + MLP head + log_softmax ----------------
__global__ __launch_bounds__(256) void k_poolhead(const _Float16* __restrict__ x,
                                                  const float* __restrict__ ss,
                                                  const int* __restrict__ gstart,
                                                  const float* __restrict__ w1, const float* __restrict__ b1,
                                                  const float* __restrict__ w2, const float* __restrict__ b2,
                                                  float* __restrict__ out) {
    int g = blockIdx.x;
    int beg = gstart[g], end = gstart[g + 1];
    int lane = threadIdx.x & 31;
    int walker = threadIdx.x >> 5;
    const half4* x4 = (const half4*)x;
    float4 sc = ((const float4*)ss)[lane];
    float4 sh = ((const float4*)(ss + 128))[lane];
    float4 acc = make_float4(0.f, 0.f, 0.f, 0.f);
    for (int r = beg + walker; r < end; r += 8) {
        half4 v = x4[(size_t)r * 32 + lane];
        acc.x += fmaxf((float)v.x * sc.x + sh.x, 0.f);
        acc.y += fmaxf((float)v.y * sc.y + sh.y, 0.f);
        acc.z += fmaxf((float)v.z * sc.z + sh.z, 0.f);
        acc.w += fmaxf((float)v.w * sc.w + sh.w, 0.f);
    }
    __shared__ float4 red[256];
    __shared__ float p[H], hh[H], lg[NC], lsred;
    red[threadIdx.x] = acc;
    __syncthreads();
    if (threadIdx.x < 32) {
        float4 s = red[threadIdx.x];
        for (int w = 1; w < 8; w++) {
            float4 v = red[w * 32 + threadIdx.x];
            s.x += v.x; s.y += v.y; s.z += v.z; s.w += v.w;
        }
        float inv = 1.0f / fmaxf((float)(end - beg), 1.0f);
        ((float4*)p)[threadIdx.x] = make_float4(s.x * inv, s.y * inv, s.z * inv, s.w * inv);
    }
    __syncthreads();
    int f = threadIdx.x;
    if (f < H) {
        float a = b1[f];
        for (int k = 0; k < H; k++) a += p[k] * w1[k * H + f];
        hh[f] = a > 0.f ? a : 0.f;
    }
    __syncthreads();
    if (f < NC) {
        float l = b2[f];
        for (int k = 0; k < H; k++) l += hh[k] * w2[k * NC + f];
        lg[f] = l;
    }
    __syncthreads();
    if (f == 0) {
        float m = lg[0];
        for (int c = 1; c < NC; c++) m = m > lg[c] ? m : lg[c];
        float s = 0.f;
        for (int c = 0; c < NC; c++) s += expf(lg[c] - m);
        lsred = m + logf(s);
    }
    __syncthreads();
    if (f < NC) out[g * NC + f] = lg[f] - lsred;
}

extern "C" void kernel_launch(void* const* d_in, const int* in_sizes, int n_in,
                              void* d_out, int out_size, void* d_ws, size_t ws_size,
                              hipStream_t stream) {
    const float* x     = (const float*)d_in[0];
    const int*   ei    = (const int*)d_in[1];
    const int*   srcp  = ei;
    const int*   dstp  = ei + NE;
    const int*   batch = (const int*)d_in[2];
    const float* W[3]  = {(const float*)d_in[3],  (const float*)d_in[7],  (const float*)d_in[11]};
    const float* b[3]  = {(const float*)d_in[4],  (const float*)d_in[8],  (const float*)d_in[12]};
    const float* gm[3] = {(const float*)d_in[5],  (const float*)d_in[9],  (const float*)d_in[13]};
    const float* bt[3] = {(const float*)d_in[6],  (const float*)d_in[10], (const float*)d_in[14]};
    const float* w1 = (const float*)d_in[15];
    const float* b1 = (const float*)d_in[16];
    const float* w2 = (const float*)d_in[17];
    const float* b2 = (const float*)d_in[18];
    float* out = (float*)d_out;

    float* ws        = (float*)d_ws;
    float* dis       = ws;                          // 100000
    int*   rowptr    = (int*)(ws + 100000);         // 100001 (pad 100004)
    int*   bbase     = (int*)(ws + 200004);         // 98 (pad 128)
    int*   gstart    = (int*)(ws + 200132);         // 101 (pad 108)
    float* ssbuf     = ws + 200240;                 // 768
    int*   bcnt      = (int*)(ws + 201008);         // 128 (adjacent to sp: one memset)
    float* sp        = ws + 201136;                 // NSLOT*256 = 65536
    _Float16* wt     = (_Float16*)(ws + 266672);    // 3*16384 halves
    int*   col       = (int*)(ws + 291248);         // NE
    unsigned int* staging = (unsigned int*)(ws + 1891248);  // NB*CAP
    _Float16* aggh   = (_Float16*)(ws + 3697584);   // NN*H f16
    unsigned char* hb = (unsigned char*)(ws + 10097584);  // NN*H fp8

    (void)hipMemsetAsync(bcnt, 0, (128 + NSLOT * 256) * sizeof(float), stream);
    k_bucket1<<<(NE + 8191) / 8192, 256, 0, stream>>>(srcp, dstp, bcnt, staging);
    k_bprefix<<<2, 128, 0, stream>>>(bcnt, bbase, rowptr, batch, gstart);
    k_bucket2<<<NB, 256, 0, stream>>>(staging, bcnt, bbase, rowptr, dis, col);
    k_prepw3<<<192, 256, 0, stream>>>(W[0], W[1], W[2], wt);

    const float* ss_prev = nullptr;
    for (int l = 0; l < 3; l++) {
        float* ss = ssbuf + l * 256;
        k_gemm<<<1024, 256, 0, stream>>>(l == 0 ? x : nullptr,
                                         l == 0 ? nullptr : aggh,
                                         ss_prev, wt + l * 16384, dis, hb);
        k_agg<<<NN / 4, 256, 0, stream>>>(hb, rowptr, col, dis, b[l], aggh, sp);
        k_stats_bss<<<1, 256, 0, stream>>>(sp, gm[l], bt[l], ss);
        ss_prev = ss;
    }

    k_poolhead<<<NG, 256, 0, stream>>>(aggh, ssbuf + 2 * 256, gstart, w1, b1, w2, b2, out);
}